// Round 3
// baseline (909.851 us; speedup 1.0000x reference)
//
#include <hip/hip_runtime.h>
#include <math.h>

#define BATCH 16384
#define IND   362
#define KP    384      // per-feature K padded to 384 (12 x 32)
#define HID   256
#define STY   60
#define NOUT  49710
#define OUTP  51200    // padded o-stride for hrows (multiple of 64)
#define D2    724
#define D2P   768

// ---- prep kernel block ranges (256 threads each) ----
#define NB_SS   120                       // style scalars + col norms (FIRST: latency-bound)
#define NB_HR   3200                      // Hrows convert: 2*64*51200/(256*8)
#define NB_CW   768                       // conv_w
#define NB_CPN  384                       // conv_pnT
#define NB_CF   9216                      // conv_feat
#define NB_PREP (NB_SS + NB_HR + NB_CW + NB_CPN + NB_CF)

// ---- main kernel block ranges ----
#define NSTRIP  777                       // ceil(NOUT/64)
#define NB_MB   (2 * NSTRIP)              // 1554 M-stream blocks (first: BW-bound)
#define NPAIR   23                        // 23 pairs of 16-row d-tiles = 736 >= 724
#define NB_EMB  1024
#define NB_SA   512
#define NB_HH   16
#define NB_PPB  2
#define NB_HEAD (NB_HH + NB_PPB)
#define NB_MAIN (NB_MB + NB_EMB + NB_SA + NB_HEAD)

typedef __bf16 bf16x8 __attribute__((ext_vector_type(8)));
typedef float  floatx4 __attribute__((ext_vector_type(4)));
typedef float  floatx2 __attribute__((ext_vector_type(2)));

__device__ inline floatx4 mfma16(bf16x8 a, bf16x8 b, floatx4 c) {
  return __builtin_amdgcn_mfma_f32_16x16x32_bf16(a, b, c, 0, 0, 0);
}

__device__ inline unsigned short f32_to_bf16(float x) {
  unsigned int u = __float_as_uint(x);
  unsigned int r = (u + 0x7FFFu + ((u >> 16) & 1u)) >> 16;
  return (unsigned short)r;
}

__device__ inline float sigm_fast(float x) { return 1.0f / (1.0f + __expf(-x)); }
__device__ inline float softplusf(float z) { return fmaxf(z, 0.0f) + log1pf(expf(-fabsf(z))); }

// =================== PHASE A: prep (style scalars + all bf16 converts) ===================
__global__ __launch_bounds__(256) void k_prep(
    const float* __restrict__ fi, const float* __restrict__ fj, const float* __restrict__ fk,
    const float* __restrict__ Wt, const float* __restrict__ btop,
    const float* __restrict__ Wb, const float* __restrict__ bbot,
    const float* __restrict__ Pn, const float* __restrict__ Nn,
    const float* __restrict__ H1, const float* __restrict__ H2,
    unsigned short* __restrict__ fbf, unsigned short* __restrict__ wbfT,
    unsigned short* __restrict__ pnbfT, unsigned short* __restrict__ hrows,
    float* __restrict__ ss, float* __restrict__ cn) {
  __shared__ float sel[D2];
  __shared__ float shr[4];
  int b = blockIdx.x;
  int t = threadIdx.x;

  if (b < NB_SS) {
    // ---- per-style scalar scores + column norms (fp32 exact) ----
    int s  = b % STY;
    int mt = b / STY;
    const float* M = mt ? Nn : Pn;
    float cnp = 0.0f;
    for (int d = t; d < D2; d += 256) {
      float v = fmaxf(M[(size_t)d * STY + s], 0.0f);
      sel[d] = v;
      cnp += v * v;
    }
    __syncthreads();
    float at = btop[t], ab = bbot[t];
    for (int d = 0; d < IND; d++) at = fmaf(sel[d],       Wt[(size_t)d * HID + t], at);
    for (int d = 0; d < IND; d++) ab = fmaf(sel[IND + d], Wb[(size_t)d * HID + t], ab);
    float prod = (1.0f / (1.0f + expf(-at))) * (1.0f / (1.0f + expf(-ab)));
    for (int off = 32; off > 0; off >>= 1) prod += __shfl_xor(prod, off);
    if ((t & 63) == 0) shr[t >> 6] = prod;
    __syncthreads();
    if (t == 0) ss[mt * 64 + s] = shr[0] + shr[1] + shr[2] + shr[3];
    __syncthreads();
    for (int off = 32; off > 0; off >>= 1) cnp += __shfl_xor(cnp, off);
    if ((t & 63) == 0) shr[t >> 6] = cnp;
    __syncthreads();
    if (t == 0) cn[mt * 64 + s] = shr[0] + shr[1] + shr[2] + shr[3];
    return;
  }
  b -= NB_SS;

  if (b < NB_HR) {
    // ---- H1/H2 relu -> hrows [2][64][51200] bf16 row-major, zero-padded ----
    int e = (b * 256 + t) * 8;
    int row = e / OUTP;
    int o = e - row * OUTP;
    int s = row & 63;
    int mm = row >> 6;
    const float* H = mm ? H2 : H1;
    unsigned short* dst = hrows + (size_t)row * OUTP + o;
    unsigned int wv[4];
    if (s < STY && o + 8 <= NOUT) {
      const float* src = H + (size_t)s * NOUT + o;
      #pragma unroll
      for (int ee = 0; ee < 4; ee++) {
        floatx2 v = *(const floatx2*)(src + 2 * ee);
        wv[ee] = (unsigned)f32_to_bf16(fmaxf(v[0], 0.0f)) |
                 ((unsigned)f32_to_bf16(fmaxf(v[1], 0.0f)) << 16);
      }
    } else {
      #pragma unroll
      for (int ee = 0; ee < 4; ee++) {
        float lo = (s < STY && o + 2 * ee     < NOUT) ? fmaxf(H[(size_t)s * NOUT + o + 2 * ee],     0.0f) : 0.0f;
        float hi = (s < STY && o + 2 * ee + 1 < NOUT) ? fmaxf(H[(size_t)s * NOUT + o + 2 * ee + 1], 0.0f) : 0.0f;
        wv[ee] = (unsigned)f32_to_bf16(lo) | ((unsigned)f32_to_bf16(hi) << 16);
      }
    }
    uint4 v; v.x = wv[0]; v.y = wv[1]; v.z = wv[2]; v.w = wv[3];
    *(uint4*)dst = v;
    return;
  }
  b -= NB_HR;

  if (b < NB_CW) {
    // ---- W -> wbfT [2][256][384] (flat) ----
    int idx = b * 256 + t;
    int k = idx % KP;
    int rem = idx / KP;
    int h = rem % HID;
    int mm = rem / HID;
    const float* W = mm ? Wb : Wt;
    wbfT[idx] = f32_to_bf16(k < IND ? W[(size_t)k * HID + h] : 0.0f);
    return;
  }
  b -= NB_CW;

  if (b < NB_CPN) {
    // ---- P/N relu -> pnbfT [2][64][768] (feature-concat k layout, zero-padded) ----
    int u = b * 256 + t;
    int s = u & 63;
    int v = u >> 6;
    int m = (v >= D2P) ? 1 : 0;
    int d = v - m * D2P;
    const float* M = m ? Nn : Pn;
    float x = (d < D2 && s < STY) ? fmaxf(M[(size_t)d * STY + s], 0.0f) : 0.0f;
    unsigned short bb = f32_to_bf16(x);
    int k = (d < IND) ? d : (d < D2 ? d + 22 : (d < 746 ? d - IND : d));
    pnbfT[((size_t)m * 64 + s) * D2P + k] = bb;
    return;
  }
  b -= NB_CPN;

  {
    // ---- features -> fbf bf16 (uint4 stores) ----
    long u = (long)b * 256 + t;
    int g = (int)(u % 48);
    long rf = u / 48;
    int row = (int)(rf % BATCH);
    int f = (int)(rf / BATCH);
    const float* src = (f == 0) ? fi : (f == 1 ? fj : fk);
    int d0 = g * 8;
    const float* sp = src + (size_t)row * IND + d0;
    unsigned int wv[4];
    #pragma unroll
    for (int e = 0; e < 4; e++) {
      int dd = d0 + 2 * e;
      float lo = (dd < IND)     ? sp[2 * e]     : 0.0f;
      float hi = (dd + 1 < IND) ? sp[2 * e + 1] : 0.0f;
      wv[e] = (unsigned)f32_to_bf16(lo) | ((unsigned)f32_to_bf16(hi) << 16);
    }
    uint4 v; v.x = wv[0]; v.y = wv[1]; v.z = wv[2]; v.w = wv[3];
    *(uint4*)(fbf + ((size_t)f * BATCH + row) * KP + d0) = v;
  }
}

// =================== PHASE B: main (M-stream first, compute blocks backfill) ===================
__global__ __launch_bounds__(256) void k_main(
    const unsigned short* __restrict__ fbf, const unsigned short* __restrict__ wbfT,
    const unsigned short* __restrict__ pnbfT, const unsigned short* __restrict__ hrows,
    const float* __restrict__ btop, const float* __restrict__ bbot,
    const float* __restrict__ cn, const float* __restrict__ ss,
    const float* __restrict__ mp, const float* __restrict__ mneg,
    const float* __restrict__ Pn, const float* __restrict__ Nn,
    float* __restrict__ sIJ, float* __restrict__ sIK,
    float* __restrict__ stIJ, float* __restrict__ stIK,
    float* __restrict__ HHb, float* __restrict__ PPb,
    float* __restrict__ partial) {
  __shared__ float red[4096];
  int w = threadIdx.x >> 6, lane = threadIdx.x & 63;
  int m = lane & 15, q = lane >> 4;
  int b = blockIdx.x;

  if (b < NB_MB) {
    // ---------- M-stream strip: 64 o-cols, H in regs, walk d in pairs of 16-row tiles ----------
    int mat   = b & 1;
    int strip = b >> 1;
    int o0 = strip * 64;
    bool full = (o0 + 64 <= NOUT);
    const float* Mbase = mat ? mneg : mp;
    const float* PM    = mat ? Nn : Pn;

    // preload H fragments for this strip: h[st][kc], rows s = st*16+m, cols o0+kc*32+q*8
    bf16x8 h[4][2];
    #pragma unroll
    for (int st = 0; st < 4; st++)
      #pragma unroll
      for (int kc = 0; kc < 2; kc++)
        h[st][kc] = *(const bf16x8*)(hrows + ((size_t)mat * 64 + st * 16 + m) * OUTP
                                     + o0 + kc * 32 + q * 8);

    float msq = 0.0f, t2 = 0.0f;
    floatx2 B0[16], B1[16];   // two named buffers: pair = 2 tiles x 2 kc x 4 floatx2

    auto LOADP = [&](int pt, floatx2* B) {
      #pragma unroll
      for (int tt = 0; tt < 2; tt++) {
        int d = pt * 32 + tt * 16 + m;
        bool ok = (pt < NPAIR) && (d < D2);
        const float* Mrow = Mbase + (size_t)d * NOUT + o0;
        #pragma unroll
        for (int kc = 0; kc < 2; kc++) {
          #pragma unroll
          for (int e = 0; e < 4; e++) {
            int oo = kc * 32 + q * 8 + 2 * e;
            floatx2 v = {0.f, 0.f};
            if (ok) {
              if (full) {
                v = *(const floatx2*)(Mrow + oo);
              } else {
                if (o0 + oo     < NOUT) v[0] = Mrow[oo];
                if (o0 + oo + 1 < NOUT) v[1] = Mrow[oo + 1];
              }
            }
            B[(tt * 2 + kc) * 4 + e] = v;
          }
        }
      }
    };

    auto COMP = [&](const floatx2* B, int pt) {
      #pragma unroll
      for (int tt = 0; tt < 2; tt++) {
        floatx4 acc[4];
        #pragma unroll
        for (int st = 0; st < 4; st++) acc[st] = (floatx4){0.f, 0.f, 0.f, 0.f};
        #pragma unroll
        for (int kc = 0; kc < 2; kc++) {
          union { unsigned int u[4]; bf16x8 v; } cv;
          #pragma unroll
          for (int e = 0; e < 4; e++) {
            floatx2 tv = B[(tt * 2 + kc) * 4 + e];
            msq = fmaf(tv[0], tv[0], msq);
            msq = fmaf(tv[1], tv[1], msq);
            cv.u[e] = (unsigned)f32_to_bf16(tv[0]) | ((unsigned)f32_to_bf16(tv[1]) << 16);
          }
          #pragma unroll
          for (int st = 0; st < 4; st++) acc[st] = mfma16(cv.v, h[st][kc], acc[st]);
        }
        // fold -2 * relu(P) .* acc (fp32 P; C/D layout: row = q*4+rg, col = st*16+m)
        #pragma unroll
        for (int st = 0; st < 4; st++) {
          int s = st * 16 + m;
          if (s < STY) {
            #pragma unroll
            for (int rg = 0; rg < 4; rg++) {
              int dd = pt * 32 + tt * 16 + q * 4 + rg;
              if (dd < D2) {
                float pv = fmaxf(PM[(size_t)dd * STY + s], 0.0f);
                t2 = fmaf(pv, acc[st][rg], t2);
              }
            }
          }
        }
      }
    };

    // software pipeline: two named buffers, unroll-by-2, no register rotation copies
    int pt0 = w;
    LOADP(pt0, B0);
    LOADP(pt0 + 4, B1);
    for (int pt = pt0; pt < NPAIR; pt += 8) {
      COMP(B0, pt);
      if (pt + 8 < NPAIR) LOADP(pt + 8, B0);
      if (pt + 4 < NPAIR) {
        COMP(B1, pt + 4);
        if (pt + 12 < NPAIR) LOADP(pt + 12, B1);
      }
    }

    float local = msq - 2.0f * t2;
    for (int off = 32; off > 0; off >>= 1) local += __shfl_xor(local, off);
    if (lane == 0) red[w] = local;
    __syncthreads();
    if (threadIdx.x == 0) partial[blockIdx.x] = red[0] + red[1] + red[2] + red[3];
    return;
  }
  b -= NB_MB;

  if (b < NB_EMB) {
    // ---------- embedding GEMMs + ij/ik scores (64 rows x 64 hidden cols per block) ----------
    int r0 = (b & 255) * 64 + w * 16;
    int hb = (b >> 8) * 64;
    const unsigned short* fi = fbf + (size_t)(r0 + m) * KP + q * 8;
    const unsigned short* fj = fi + (size_t)BATCH * KP;
    const unsigned short* fk = fj + (size_t)BATCH * KP;
    floatx4 accI[4], accJ[4], accK[4];
    #pragma unroll
    for (int nt = 0; nt < 4; nt++) {
      accI[nt] = (floatx4){0.f, 0.f, 0.f, 0.f};
      accJ[nt] = (floatx4){0.f, 0.f, 0.f, 0.f};
      accK[nt] = (floatx4){0.f, 0.f, 0.f, 0.f};
    }
    for (int kc = 0; kc < 12; kc++) {
      bf16x8 ai = *(const bf16x8*)(fi + kc * 32);
      bf16x8 aj = *(const bf16x8*)(fj + kc * 32);
      bf16x8 ak = *(const bf16x8*)(fk + kc * 32);
      #pragma unroll
      for (int nt = 0; nt < 4; nt++) {
        int n = hb + nt * 16 + m;
        const unsigned short* wp = wbfT + (size_t)n * KP + kc * 32 + q * 8;
        bf16x8 bt8 = *(const bf16x8*)(wp);
        bf16x8 bb8 = *(const bf16x8*)(wp + (size_t)HID * KP);
        accI[nt] = mfma16(ai, bt8, accI[nt]);
        accJ[nt] = mfma16(aj, bb8, accJ[nt]);
        accK[nt] = mfma16(ak, bb8, accK[nt]);
      }
    }
    float sij[4] = {0.f, 0.f, 0.f, 0.f}, sik[4] = {0.f, 0.f, 0.f, 0.f};
    #pragma unroll
    for (int nt = 0; nt < 4; nt++) {
      int n = hb + nt * 16 + m;
      float vbt = btop[n], vbb = bbot[n];
      #pragma unroll
      for (int reg = 0; reg < 4; reg++) {
        float ti = sigm_fast(accI[nt][reg] + vbt);
        float tj = sigm_fast(accJ[nt][reg] + vbb);
        float tk = sigm_fast(accK[nt][reg] + vbb);
        sij[reg] += ti * tj;
        sik[reg] += ti * tk;
      }
    }
    #pragma unroll
    for (int reg = 0; reg < 4; reg++) {
      for (int off = 1; off < 16; off <<= 1) {
        sij[reg] += __shfl_xor(sij[reg], off);
        sik[reg] += __shfl_xor(sik[reg], off);
      }
    }
    if (m == 0) {
      #pragma unroll
      for (int reg = 0; reg < 4; reg++) {
        int row = r0 + q * 4 + reg;
        atomicAdd(&sIJ[row], sij[reg]);
        atomicAdd(&sIK[row], sik[reg]);
      }
    }
    return;
  }
  b -= NB_EMB;

  if (b < NB_SA) {
    // ---------- style argmin + gather ----------
    int mat = w & 1;
    int r0 = b * 32 + (w >> 1) * 16;
    const unsigned short* fA = fbf + (size_t)(r0 + m) * KP + q * 8;
    const unsigned short* fB = fA + (size_t)(1 + mat) * BATCH * KP;
    const unsigned short* Bp = pnbfT + (size_t)mat * 64 * D2P + q * 8;
    floatx4 acc[4];
    #pragma unroll
    for (int nt = 0; nt < 4; nt++) acc[nt] = (floatx4){0.f, 0.f, 0.f, 0.f};
    for (int kc = 0; kc < 24; kc++) {
      bf16x8 a = (kc < 12) ? *(const bf16x8*)(fA + kc * 32)
                           : *(const bf16x8*)(fB + (kc - 12) * 32);
      #pragma unroll
      for (int nt = 0; nt < 4; nt++) {
        bf16x8 bb = *(const bf16x8*)(Bp + (size_t)(nt * 16 + m) * D2P + kc * 32);
        acc[nt] = mfma16(a, bb, acc[nt]);
      }
    }
    const float* cnm = cn + mat * 64;
    float bv[4]; int bi[4];
    #pragma unroll
    for (int reg = 0; reg < 4; reg++) { bv[reg] = __builtin_inff(); bi[reg] = 1 << 30; }
    #pragma unroll
    for (int nt = 0; nt < 4; nt++) {
      int s = nt * 16 + m;
      float c = cnm[s & 63];
      #pragma unroll
      for (int reg = 0; reg < 4; reg++) {
        float d2 = (s < STY) ? (c - 2.0f * acc[nt][reg]) : __builtin_inff();
        if (d2 < bv[reg] || (d2 == bv[reg] && s < bi[reg])) { bv[reg] = d2; bi[reg] = s; }
      }
    }
    for (int off = 1; off < 16; off <<= 1) {
      #pragma unroll
      for (int reg = 0; reg < 4; reg++) {
        float ov = __shfl_xor(bv[reg], off);
        int   oi = __shfl_xor(bi[reg], off);
        if (ov < bv[reg] || (ov == bv[reg] && oi < bi[reg])) { bv[reg] = ov; bi[reg] = oi; }
      }
    }
    if (m == 0) {
      float* dst = mat ? stIK : stIJ;
      const float* ssm = ss + mat * 64;
      #pragma unroll
      for (int reg = 0; reg < 4; reg++) dst[r0 + q * 4 + reg] = ssm[bi[reg]];
    }
    return;
  }
  b -= NB_SA;

  {
    // ---------- HH^T (16 blocks) and P^T P (2 blocks) gram matrices ----------
    bool isPP = (b >= NB_HH);
    int mat, chunk, nsteps, stride;
    const unsigned short* Rb;
    if (!isPP) { mat = b >> 3; chunk = b & 7; Rb = hrows + (size_t)mat * 64 * OUTP; stride = OUTP; nsteps = 200; }
    else       { mat = b - NB_HH; chunk = 0; Rb = pnbfT + (size_t)mat * 64 * D2P;  stride = D2P;  nsteps = 24;  }
    const unsigned short* Rm = Rb + (size_t)m * stride;

    floatx4 acc[4][4];
    #pragma unroll
    for (int a2 = 0; a2 < 4; a2++)
      #pragma unroll
      for (int b2 = 0; b2 < 4; b2++) acc[a2][b2] = (floatx4){0.f, 0.f, 0.f, 0.f};

    bf16x8 hc[4], hn[4];
    auto LD = [&](int j, bf16x8* hh) {
      int k = (chunk * nsteps + j) * 32 + q * 8;
      #pragma unroll
      for (int st = 0; st < 4; st++)
        hh[st] = *(const bf16x8*)(Rm + (size_t)(st * 16) * stride + k);
    };
    int j = w;
    LD(j, hc);
    for (; j < nsteps; j += 4) {
      if (j + 4 < nsteps) LD(j + 4, hn);
      #pragma unroll
      for (int a2 = 0; a2 < 4; a2++)
        #pragma unroll
        for (int b2 = 0; b2 < 4; b2++)
          acc[a2][b2] = mfma16(hc[a2], hc[b2], acc[a2][b2]);
      #pragma unroll
      for (int st = 0; st < 4; st++) hc[st] = hn[st];
    }
    for (int idx = threadIdx.x; idx < 4096; idx += 256) red[idx] = 0.f;
    __syncthreads();
    #pragma unroll
    for (int a2 = 0; a2 < 4; a2++)
      #pragma unroll
      for (int b2 = 0; b2 < 4; b2++)
        #pragma unroll
        for (int r = 0; r < 4; r++)
          atomicAdd(&red[(a2 * 16 + q * 4 + r) * 64 + b2 * 16 + m], acc[a2][b2][r]);
    __syncthreads();
    float* dst = (isPP ? PPb : HHb) + (size_t)mat * 4096;
    for (int idx = threadIdx.x; idx < 4096; idx += 256) atomicAdd(&dst[idx], red[idx]);
  }
}

// =================== PHASE C: final reductions ===================
__global__ __launch_bounds__(256) void k_final(
    const float* __restrict__ sIJ, const float* __restrict__ sIK,
    const float* __restrict__ stIJ, const float* __restrict__ stIK,
    const float* __restrict__ l3partial,
    const float* __restrict__ HHb, const float* __restrict__ PPb,
    float* __restrict__ out) {
  int t = threadIdx.x;
  float l1 = 0.f, l2 = 0.f, ac = 0.f;
  for (int r = t; r < BATCH; r += 256) {
    float dij = sIJ[r] - sIK[r];
    l1 += softplusf(-dij);
    if (dij >= 0.0f) ac += 1.0f;
    float dst = stIJ[r] - stIK[r];
    l2 += softplusf(-dst);
  }
  double l3 = 0.0;
  for (int p = t; p < NB_MB; p += 256) l3 += (double)l3partial[p];
  for (int idx = t; idx < 8192; idx += 256) l3 += (double)HHb[idx] * (double)PPb[idx];
  __shared__ float sh1[4], sh2[4], sh3[4];
  __shared__ double sh4[4];
  for (int off = 32; off > 0; off >>= 1) {
    l1 += __shfl_xor(l1, off);
    l2 += __shfl_xor(l2, off);
    ac += __shfl_xor(ac, off);
    l3 += __shfl_xor(l3, off);
  }
  if ((t & 63) == 0) { sh1[t >> 6] = l1; sh2[t >> 6] = l2; sh3[t >> 6] = ac; sh4[t >> 6] = l3; }
  __syncthreads();
  if (t == 0) {
    double L1 = 0, L2 = 0, AC = 0, L3 = 0;
    for (int i = 0; i < 4; i++) { L1 += sh1[i]; L2 += sh2[i]; AC += sh3[i]; L3 += sh4[i]; }
    L1 /= BATCH; L2 /= BATCH; AC /= BATCH;
    L3 /= ((double)D2 * (double)NOUT);
    out[0] = (float)(L1 + L2 + 0.1 * L3);
    out[1] = (float)L1;
    out[2] = (float)L2;
    out[3] = (float)L3;
    out[4] = (float)AC;
  }
}

extern "C" void kernel_launch(void* const* d_in, const int* in_sizes, int n_in,
                              void* d_out, int out_size, void* d_ws, size_t ws_size,
                              hipStream_t stream) {
  (void)in_sizes; (void)n_in; (void)out_size; (void)ws_size;
  const float* i_f  = (const float*)d_in[0];
  const float* j_f  = (const float*)d_in[1];
  const float* k_f  = (const float*)d_in[2];
  const float* W_t  = (const float*)d_in[3];
  const float* b_t  = (const float*)d_in[4];
  const float* W_b  = (const float*)d_in[5];
  const float* b_b  = (const float*)d_in[6];
  const float* P_n  = (const float*)d_in[7];
  const float* N_n  = (const float*)d_in[8];
  const float* H1   = (const float*)d_in[9];
  const float* H2   = (const float*)d_in[10];
  const float* Mp   = (const float*)d_in[11];
  const float* Mn   = (const float*)d_in[12];
  float* out = (float*)d_out;
  char* ws = (char*)d_ws;

  const size_t OFF_FBF   = 0;
  const size_t OFF_WBFT  = OFF_FBF   + (size_t)3 * BATCH * KP * 2;
  const size_t OFF_PNBFT = OFF_WBFT  + (size_t)2 * HID * KP * 2;
  const size_t OFF_HROWS = OFF_PNBFT + (size_t)2 * 64 * D2P * 2;
  const size_t OFF_SIJ   = OFF_HROWS + (size_t)2 * 64 * OUTP * 2;
  const size_t OFF_SIK   = OFF_SIJ   + (size_t)BATCH * 4;
  const size_t OFF_HH    = OFF_SIK   + (size_t)BATCH * 4;
  const size_t OFF_PP    = OFF_HH    + (size_t)2 * 4096 * 4;
  const size_t OFF_STIJ  = OFF_PP    + (size_t)2 * 4096 * 4;
  const size_t OFF_STIK  = OFF_STIJ  + (size_t)BATCH * 4;
  const size_t OFF_SS    = OFF_STIK  + (size_t)BATCH * 4;
  const size_t OFF_CN    = OFF_SS    + 512;
  const size_t OFF_L3P   = OFF_CN    + 512;

  unsigned short* fbf   = (unsigned short*)(ws + OFF_FBF);
  unsigned short* wbfT  = (unsigned short*)(ws + OFF_WBFT);
  unsigned short* pnbfT = (unsigned short*)(ws + OFF_PNBFT);
  unsigned short* hrows = (unsigned short*)(ws + OFF_HROWS);
  float*  sIJ  = (float*)(ws + OFF_SIJ);
  float*  sIK  = (float*)(ws + OFF_SIK);
  float*  HHb  = (float*)(ws + OFF_HH);
  float*  PPb  = (float*)(ws + OFF_PP);
  float*  stIJ = (float*)(ws + OFF_STIJ);
  float*  stIK = (float*)(ws + OFF_STIK);
  float*  ss   = (float*)(ws + OFF_SS);
  float*  cn   = (float*)(ws + OFF_CN);
  float*  l3p  = (float*)(ws + OFF_L3P);

  // zero: sIJ, sIK, HH, PP (atomic targets) — contiguous
  hipMemsetAsync(ws + OFF_SIJ, 0, (size_t)BATCH * 4 * 2 + (size_t)4 * 4096 * 4, stream);

  k_prep<<<NB_PREP, 256, 0, stream>>>(i_f, j_f, k_f, W_t, b_t, W_b, b_b,
                                      P_n, N_n, H1, H2,
                                      fbf, wbfT, pnbfT, hrows, ss, cn);
  k_main<<<NB_MAIN, 256, 0, stream>>>(fbf, wbfT, pnbfT, hrows,
                                      b_t, b_b, cn, ss, Mp, Mn, P_n, N_n,
                                      sIJ, sIK, stIJ, stIK, HHb, PPb, l3p);
  k_final<<<1, 256, 0, stream>>>(sIJ, sIK, stIJ, stIK, l3p, HHb, PPb, out);
}

// Round 4
// 698.622 us; speedup vs baseline: 1.3024x; 1.3024x over previous
//
#include <hip/hip_runtime.h>
#include <math.h>

#define BATCH 16384
#define IND   362
#define KP    384      // per-feature K padded to 384 (12 x 32)
#define HID   256
#define STY   60
#define NOUT  49710
#define OUTP  49920    // padded o-stride for hrows (= 195 * 256), zero-padded
#define D2    724
#define D2P   768

// ---- conv kernel block ranges (256 threads each) ----
#define NB_HR   3120                      // Hrows convert: 2*64*49920/(256*8)
#define NB_CW   768                       // conv_w
#define NB_CPN  384                       // conv_pnT + Pr fp32
#define NB_CF   9216                      // conv_feat
#define NB_CONV (NB_HR + NB_CW + NB_CPN + NB_CF)

#define NB_SS   120                       // style_scalar kernel

// ---- M-stream kernel ----
#define OCH     256                       // o-chunk (1 KB per row run)
#define N_OC    195                       // 49920 / 256
#define DHALF   368                       // 23 tiles of 16
#define NTILES  23
#define NB_M    (2 * 2 * N_OC)            // mats x d-halves x o-chunks = 780

#define NB_EMB  1024
#define NB_SA   512
#define NB_HH   16
#define NB_PPB  2
#define NB_HEAD (NB_HH + NB_PPB)

typedef __bf16 bf16x8 __attribute__((ext_vector_type(8)));
typedef float  floatx4 __attribute__((ext_vector_type(4)));
typedef float  floatx2 __attribute__((ext_vector_type(2)));

__device__ inline floatx4 mfma16(bf16x8 a, bf16x8 b, floatx4 c) {
  return __builtin_amdgcn_mfma_f32_16x16x32_bf16(a, b, c, 0, 0, 0);
}

__device__ inline unsigned short f32_to_bf16(float x) {
  unsigned int u = __float_as_uint(x);
  unsigned int r = (u + 0x7FFFu + ((u >> 16) & 1u)) >> 16;
  return (unsigned short)r;
}

__device__ inline float sigm_fast(float x) { return 1.0f / (1.0f + __expf(-x)); }
__device__ inline float softplusf(float z) { return fmaxf(z, 0.0f) + log1pf(expf(-fabsf(z))); }

// =================== conv: all bf16 converts + Pr fp32 ===================
__global__ __launch_bounds__(256) void k_conv(
    const float* __restrict__ fi, const float* __restrict__ fj, const float* __restrict__ fk,
    const float* __restrict__ Wt, const float* __restrict__ Wb,
    const float* __restrict__ Pn, const float* __restrict__ Nn,
    const float* __restrict__ H1, const float* __restrict__ H2,
    unsigned short* __restrict__ fbf, unsigned short* __restrict__ wbfT,
    unsigned short* __restrict__ pnbfT, unsigned short* __restrict__ hrows,
    float* __restrict__ Pr) {
  int b = blockIdx.x;
  int t = threadIdx.x;

  if (b < NB_HR) {
    // ---- H1/H2 relu -> hrows [2][64][49920] bf16 row-major, zero-padded ----
    int e = (b * 256 + t) * 8;
    int row = e / OUTP;
    int o = e - row * OUTP;
    int s = row & 63;
    int mm = row >> 6;
    const float* H = mm ? H2 : H1;
    unsigned short* dst = hrows + (size_t)row * OUTP + o;
    unsigned int wv[4];
    if (s < STY && o + 8 <= NOUT) {
      const float* src = H + (size_t)s * NOUT + o;
      #pragma unroll
      for (int ee = 0; ee < 4; ee++) {
        floatx2 v = *(const floatx2*)(src + 2 * ee);
        wv[ee] = (unsigned)f32_to_bf16(fmaxf(v[0], 0.0f)) |
                 ((unsigned)f32_to_bf16(fmaxf(v[1], 0.0f)) << 16);
      }
    } else {
      #pragma unroll
      for (int ee = 0; ee < 4; ee++) {
        float lo = (s < STY && o + 2 * ee     < NOUT) ? fmaxf(H[(size_t)s * NOUT + o + 2 * ee],     0.0f) : 0.0f;
        float hi = (s < STY && o + 2 * ee + 1 < NOUT) ? fmaxf(H[(size_t)s * NOUT + o + 2 * ee + 1], 0.0f) : 0.0f;
        wv[ee] = (unsigned)f32_to_bf16(lo) | ((unsigned)f32_to_bf16(hi) << 16);
      }
    }
    uint4 v; v.x = wv[0]; v.y = wv[1]; v.z = wv[2]; v.w = wv[3];
    *(uint4*)dst = v;
    return;
  }
  b -= NB_HR;

  if (b < NB_CW) {
    // ---- W -> wbfT [2][256][384] (flat) ----
    int idx = b * 256 + t;
    int k = idx % KP;
    int rem = idx / KP;
    int h = rem % HID;
    int mm = rem / HID;
    const float* W = mm ? Wb : Wt;
    wbfT[idx] = f32_to_bf16(k < IND ? W[(size_t)k * HID + h] : 0.0f);
    return;
  }
  b -= NB_CW;

  if (b < NB_CPN) {
    // ---- P/N relu -> pnbfT [2][64][768] bf16 + Pr [2][768][64] fp32 (both zero-padded) ----
    int u = b * 256 + t;
    int s = u & 63;
    int v = u >> 6;
    int m = (v >= D2P) ? 1 : 0;
    int d = v - m * D2P;
    const float* M = m ? Nn : Pn;
    float x = (d < D2 && s < STY) ? fmaxf(M[(size_t)d * STY + s], 0.0f) : 0.0f;
    unsigned short bb = f32_to_bf16(x);
    int k = (d < IND) ? d : (d < D2 ? d + 22 : (d < 746 ? d - IND : d));
    pnbfT[((size_t)m * 64 + s) * D2P + k] = bb;
    Pr[((size_t)m * D2P + d) * 64 + s] = x;
    return;
  }
  b -= NB_CPN;

  {
    // ---- features -> fbf bf16 (uint4 stores) ----
    long u = (long)b * 256 + t;
    int g = (int)(u % 48);
    long rf = u / 48;
    int row = (int)(rf % BATCH);
    int f = (int)(rf / BATCH);
    const float* src = (f == 0) ? fi : (f == 1 ? fj : fk);
    int d0 = g * 8;
    const float* sp = src + (size_t)row * IND + d0;
    unsigned int wv[4];
    #pragma unroll
    for (int e = 0; e < 4; e++) {
      int dd = d0 + 2 * e;
      float lo = (dd < IND)     ? sp[2 * e]     : 0.0f;
      float hi = (dd + 1 < IND) ? sp[2 * e + 1] : 0.0f;
      wv[e] = (unsigned)f32_to_bf16(lo) | ((unsigned)f32_to_bf16(hi) << 16);
    }
    uint4 v; v.x = wv[0]; v.y = wv[1]; v.z = wv[2]; v.w = wv[3];
    *(uint4*)(fbf + ((size_t)f * BATCH + row) * KP + d0) = v;
  }
}

// =================== style scalar scores + column norms (fp32 exact) ===================
__global__ __launch_bounds__(256) void k_style(
    const float* __restrict__ Wt, const float* __restrict__ btop,
    const float* __restrict__ Wb, const float* __restrict__ bbot,
    const float* __restrict__ Pn, const float* __restrict__ Nn,
    float* __restrict__ ss, float* __restrict__ cn) {
  __shared__ float sel[D2];
  __shared__ float shr[4];
  int b = blockIdx.x;
  int t = threadIdx.x;
  int s  = b % STY;
  int mt = b / STY;
  const float* M = mt ? Nn : Pn;
  float cnp = 0.0f;
  for (int d = t; d < D2; d += 256) {
    float v = fmaxf(M[(size_t)d * STY + s], 0.0f);
    sel[d] = v;
    cnp += v * v;
  }
  __syncthreads();
  float at = btop[t], ab = bbot[t];
  for (int d = 0; d < IND; d++) at = fmaf(sel[d],       Wt[(size_t)d * HID + t], at);
  for (int d = 0; d < IND; d++) ab = fmaf(sel[IND + d], Wb[(size_t)d * HID + t], ab);
  float prod = (1.0f / (1.0f + expf(-at))) * (1.0f / (1.0f + expf(-ab)));
  for (int off = 32; off > 0; off >>= 1) prod += __shfl_xor(prod, off);
  if ((t & 63) == 0) shr[t >> 6] = prod;
  __syncthreads();
  if (t == 0) ss[mt * 64 + s] = shr[0] + shr[1] + shr[2] + shr[3];
  __syncthreads();
  for (int off = 32; off > 0; off >>= 1) cnp += __shfl_xor(cnp, off);
  if ((t & 63) == 0) shr[t >> 6] = cnp;
  __syncthreads();
  if (t == 0) cn[mt * 64 + s] = shr[0] + shr[1] + shr[2] + shr[3];
}

// =================== M-stream: contiguous 1-KB row runs, H in LDS, C=[s][d] ===================
__global__ __launch_bounds__(256) void k_m(
    const unsigned short* __restrict__ hrows, const float* __restrict__ Pr,
    const float* __restrict__ mp, const float* __restrict__ mneg,
    float* __restrict__ partial) {
  __shared__ unsigned short Hs[64 * OCH];   // 32 KB, XOR-swizzled
  __shared__ float red[4];
  int w = threadIdx.x >> 6, lane = threadIdx.x & 63;
  int m = lane & 15, q = lane >> 4;

  int b = blockIdx.x;
  int oc  = b % N_OC;
  int r   = b / N_OC;
  int dh  = r & 1;
  int mat = r >> 1;
  int o0 = oc * OCH;
  bool full = (o0 + OCH <= NOUT);
  const float* Mbase = mat ? mneg : mp;
  const float* Prb   = Pr + (size_t)mat * D2P * 64;

  // ---- stage H[64][256] bf16 into swizzled LDS (each wave: 16 rows) ----
  char* HsB = (char*)Hs;
  #pragma unroll
  for (int rr = 0; rr < 16; rr++) {
    int R = w * 16 + rr;
    uint2 hv = *(const uint2*)(hrows + ((size_t)mat * 64 + R) * OUTP + o0 + lane * 4);
    *(uint2*)(HsB + R * 512 + ((lane * 8) ^ ((R & 7) << 4))) = hv;
  }
  __syncthreads();

  int xm = (m & 7) << 4;
  float msq = 0.0f, t2 = 0.0f;
  floatx2 mreg[32];
  floatx4 preg[4];

  auto ISSUE_M = [&](int t) {
    int d = dh * DHALF + t * 16 + m;
    bool ok = (d < D2);
    const float* Mr = Mbase + (size_t)d * NOUT + o0 + q * 8;
    if (ok && full) {
      #pragma unroll
      for (int kc = 0; kc < 8; kc++) {
        mreg[kc * 4 + 0] = *(const floatx2*)(Mr + kc * 32);
        mreg[kc * 4 + 1] = *(const floatx2*)(Mr + kc * 32 + 2);
        mreg[kc * 4 + 2] = *(const floatx2*)(Mr + kc * 32 + 4);
        mreg[kc * 4 + 3] = *(const floatx2*)(Mr + kc * 32 + 6);
      }
    } else {
      #pragma unroll
      for (int kc = 0; kc < 8; kc++) {
        #pragma unroll
        for (int e = 0; e < 4; e++) {
          int o = o0 + kc * 32 + q * 8 + 2 * e;
          floatx2 v = {0.f, 0.f};
          if (ok) {
            if (o     < NOUT) v[0] = Mbase[(size_t)d * NOUT + o];
            if (o + 1 < NOUT) v[1] = Mbase[(size_t)d * NOUT + o + 1];
          }
          mreg[kc * 4 + e] = v;
        }
      }
    }
  };
  auto ISSUE_P = [&](int t) {
    int d = dh * DHALF + t * 16 + m;   // < 768 always; Pr zero-padded
    const float* Pp = Prb + (size_t)d * 64 + q * 4;
    #pragma unroll
    for (int st = 0; st < 4; st++) preg[st] = *(const floatx4*)(Pp + st * 16);
  };

  int t0 = w;
  if (t0 < NTILES) { ISSUE_M(t0); ISSUE_P(t0); }
  for (int t = t0; t < NTILES; t += 4) {
    // CONVERT (waits mreg; preg younger stays in flight) + msq
    bf16x8 bf[8];
    #pragma unroll
    for (int kc = 0; kc < 8; kc++) {
      union { unsigned int u[4]; bf16x8 v; } cv;
      #pragma unroll
      for (int e = 0; e < 4; e++) {
        floatx2 tv = mreg[kc * 4 + e];
        msq = fmaf(tv[0], tv[0], msq);
        msq = fmaf(tv[1], tv[1], msq);
        cv.u[e] = (unsigned)f32_to_bf16(tv[0]) | ((unsigned)f32_to_bf16(tv[1]) << 16);
      }
      bf[kc] = cv.v;
    }
    int tn = t + 4;
    if (tn < NTILES) ISSUE_M(tn);       // mreg free; in flight across MFMA+FOLD

    // MFMA: A = H (LDS, lgkmcnt), B = M (regs) -> C[s][d]
    floatx4 acc[4];
    #pragma unroll
    for (int st = 0; st < 4; st++) acc[st] = (floatx4){0.f, 0.f, 0.f, 0.f};
    #pragma unroll
    for (int kc = 0; kc < 8; kc++) {
      #pragma unroll
      for (int st = 0; st < 4; st++) {
        bf16x8 hf = *(const bf16x8*)(HsB + (st * 16 + m) * 512 + ((kc * 64 + q * 16) ^ xm));
        acc[st] = mfma16(hf, bf[kc], acc[st]);
      }
    }

    // FOLD (waits preg -- issued a full phase ago, older than mreg prefetch)
    #pragma unroll
    for (int st = 0; st < 4; st++)
      #pragma unroll
      for (int rg = 0; rg < 4; rg++)
        t2 = fmaf(preg[st][rg], acc[st][rg], t2);
    if (tn < NTILES) ISSUE_P(tn);
  }

  float local = msq - 2.0f * t2;
  for (int off = 32; off > 0; off >>= 1) local += __shfl_xor(local, off);
  if (lane == 0) red[w] = local;
  __syncthreads();
  if (threadIdx.x == 0) partial[blockIdx.x] = red[0] + red[1] + red[2] + red[3];
}

// =================== embedding GEMMs + ij/ik scores ===================
__global__ __launch_bounds__(256, 4) void k_emb(
    const unsigned short* __restrict__ fbf, const unsigned short* __restrict__ wbfT,
    const float* __restrict__ btop, const float* __restrict__ bbot,
    float* __restrict__ sIJ, float* __restrict__ sIK) {
  int w = threadIdx.x >> 6, lane = threadIdx.x & 63;
  int m = lane & 15, q = lane >> 4;
  int b = blockIdx.x;
  int r0 = (b & 255) * 64 + w * 16;
  int hb = (b >> 8) * 64;
  const unsigned short* fi = fbf + (size_t)(r0 + m) * KP + q * 8;
  const unsigned short* fj = fi + (size_t)BATCH * KP;
  const unsigned short* fk = fj + (size_t)BATCH * KP;
  floatx4 accI[4], accJ[4], accK[4];
  #pragma unroll
  for (int nt = 0; nt < 4; nt++) {
    accI[nt] = (floatx4){0.f, 0.f, 0.f, 0.f};
    accJ[nt] = (floatx4){0.f, 0.f, 0.f, 0.f};
    accK[nt] = (floatx4){0.f, 0.f, 0.f, 0.f};
  }
  for (int kc = 0; kc < 12; kc++) {
    bf16x8 ai = *(const bf16x8*)(fi + kc * 32);
    bf16x8 aj = *(const bf16x8*)(fj + kc * 32);
    bf16x8 ak = *(const bf16x8*)(fk + kc * 32);
    #pragma unroll
    for (int nt = 0; nt < 4; nt++) {
      int n = hb + nt * 16 + m;
      const unsigned short* wp = wbfT + (size_t)n * KP + kc * 32 + q * 8;
      bf16x8 bt8 = *(const bf16x8*)(wp);
      bf16x8 bb8 = *(const bf16x8*)(wp + (size_t)HID * KP);
      accI[nt] = mfma16(ai, bt8, accI[nt]);
      accJ[nt] = mfma16(aj, bb8, accJ[nt]);
      accK[nt] = mfma16(ak, bb8, accK[nt]);
    }
  }
  float sij[4] = {0.f, 0.f, 0.f, 0.f}, sik[4] = {0.f, 0.f, 0.f, 0.f};
  #pragma unroll
  for (int nt = 0; nt < 4; nt++) {
    int n = hb + nt * 16 + m;
    float vbt = btop[n], vbb = bbot[n];
    #pragma unroll
    for (int reg = 0; reg < 4; reg++) {
      float ti = sigm_fast(accI[nt][reg] + vbt);
      float tj = sigm_fast(accJ[nt][reg] + vbb);
      float tk = sigm_fast(accK[nt][reg] + vbb);
      sij[reg] += ti * tj;
      sik[reg] += ti * tk;
    }
  }
  #pragma unroll
  for (int reg = 0; reg < 4; reg++) {
    for (int off = 1; off < 16; off <<= 1) {
      sij[reg] += __shfl_xor(sij[reg], off);
      sik[reg] += __shfl_xor(sik[reg], off);
    }
  }
  if (m == 0) {
    #pragma unroll
    for (int reg = 0; reg < 4; reg++) {
      int row = r0 + q * 4 + reg;
      atomicAdd(&sIJ[row], sij[reg]);
      atomicAdd(&sIK[row], sik[reg]);
    }
  }
}

// =================== style argmin + gather ===================
__global__ __launch_bounds__(256, 4) void k_sa(
    const unsigned short* __restrict__ fbf, const unsigned short* __restrict__ pnbfT,
    const float* __restrict__ cn, const float* __restrict__ ss,
    float* __restrict__ stIJ, float* __restrict__ stIK) {
  int w = threadIdx.x >> 6, lane = threadIdx.x & 63;
  int m = lane & 15, q = lane >> 4;
  int b = blockIdx.x;
  int mat = w & 1;
  int r0 = b * 32 + (w >> 1) * 16;
  const unsigned short* fA = fbf + (size_t)(r0 + m) * KP + q * 8;
  const unsigned short* fB = fA + (size_t)(1 + mat) * BATCH * KP;
  const unsigned short* Bp = pnbfT + (size_t)mat * 64 * D2P + q * 8;
  floatx4 acc[4];
  #pragma unroll
  for (int nt = 0; nt < 4; nt++) acc[nt] = (floatx4){0.f, 0.f, 0.f, 0.f};
  for (int kc = 0; kc < 24; kc++) {
    bf16x8 a = (kc < 12) ? *(const bf16x8*)(fA + kc * 32)
                         : *(const bf16x8*)(fB + (kc - 12) * 32);
    #pragma unroll
    for (int nt = 0; nt < 4; nt++) {
      bf16x8 bb = *(const bf16x8*)(Bp + (size_t)(nt * 16 + m) * D2P + kc * 32);
      acc[nt] = mfma16(a, bb, acc[nt]);
    }
  }
  const float* cnm = cn + mat * 64;
  float bv[4]; int bi[4];
  #pragma unroll
  for (int reg = 0; reg < 4; reg++) { bv[reg] = __builtin_inff(); bi[reg] = 1 << 30; }
  #pragma unroll
  for (int nt = 0; nt < 4; nt++) {
    int s = nt * 16 + m;
    float c = cnm[s & 63];
    #pragma unroll
    for (int reg = 0; reg < 4; reg++) {
      float d2 = (s < STY) ? (c - 2.0f * acc[nt][reg]) : __builtin_inff();
      if (d2 < bv[reg] || (d2 == bv[reg] && s < bi[reg])) { bv[reg] = d2; bi[reg] = s; }
    }
  }
  for (int off = 1; off < 16; off <<= 1) {
    #pragma unroll
    for (int reg = 0; reg < 4; reg++) {
      float ov = __shfl_xor(bv[reg], off);
      int   oi = __shfl_xor(bi[reg], off);
      if (ov < bv[reg] || (ov == bv[reg] && oi < bi[reg])) { bv[reg] = ov; bi[reg] = oi; }
    }
  }
  if (m == 0) {
    float* dst = mat ? stIK : stIJ;
    const float* ssm = ss + mat * 64;
    #pragma unroll
    for (int reg = 0; reg < 4; reg++) dst[r0 + q * 4 + reg] = ssm[bi[reg]];
  }
}

// =================== HH^T and P^T P gram matrices ===================
__global__ __launch_bounds__(256) void k_head(
    const unsigned short* __restrict__ pnbfT, const unsigned short* __restrict__ hrows,
    float* __restrict__ HHb, float* __restrict__ PPb) {
  __shared__ float red[4096];
  int w = threadIdx.x >> 6, lane = threadIdx.x & 63;
  int m = lane & 15, q = lane >> 4;
  int b = blockIdx.x;
  bool isPP = (b >= NB_HH);
  int mat, chunk, nsteps, stride;
  const unsigned short* Rb;
  if (!isPP) { mat = b >> 3; chunk = b & 7; Rb = hrows + (size_t)mat * 64 * OUTP; stride = OUTP; nsteps = 195; }
  else       { mat = b - NB_HH; chunk = 0; Rb = pnbfT + (size_t)mat * 64 * D2P;  stride = D2P;  nsteps = 24;  }
  const unsigned short* Rm = Rb + (size_t)m * stride;

  floatx4 acc[4][4];
  #pragma unroll
  for (int a2 = 0; a2 < 4; a2++)
    #pragma unroll
    for (int b2 = 0; b2 < 4; b2++) acc[a2][b2] = (floatx4){0.f, 0.f, 0.f, 0.f};

  bf16x8 hc[4], hn[4];
  auto LD = [&](int j, bf16x8* hh) {
    int k = (chunk * nsteps + j) * 32 + q * 8;
    #pragma unroll
    for (int st = 0; st < 4; st++)
      hh[st] = *(const bf16x8*)(Rm + (size_t)(st * 16) * stride + k);
  };
  int j = w;
  LD(j, hc);
  for (; j < nsteps; j += 4) {
    if (j + 4 < nsteps) LD(j + 4, hn);
    #pragma unroll
    for (int a2 = 0; a2 < 4; a2++)
      #pragma unroll
      for (int b2 = 0; b2 < 4; b2++)
        acc[a2][b2] = mfma16(hc[a2], hc[b2], acc[a2][b2]);
    #pragma unroll
    for (int st = 0; st < 4; st++) hc[st] = hn[st];
  }
  for (int idx = threadIdx.x; idx < 4096; idx += 256) red[idx] = 0.f;
  __syncthreads();
  #pragma unroll
  for (int a2 = 0; a2 < 4; a2++)
    #pragma unroll
    for (int b2 = 0; b2 < 4; b2++)
      #pragma unroll
      for (int r = 0; r < 4; r++)
        atomicAdd(&red[(a2 * 16 + q * 4 + r) * 64 + b2 * 16 + m], acc[a2][b2][r]);
  __syncthreads();
  float* dst = (isPP ? PPb : HHb) + (size_t)mat * 4096;
  for (int idx = threadIdx.x; idx < 4096; idx += 256) atomicAdd(&dst[idx], red[idx]);
}

// =================== final reductions ===================
__global__ __launch_bounds__(256) void k_final(
    const float* __restrict__ sIJ, const float* __restrict__ sIK,
    const float* __restrict__ stIJ, const float* __restrict__ stIK,
    const float* __restrict__ l3partial,
    const float* __restrict__ HHb, const float* __restrict__ PPb,
    float* __restrict__ out) {
  int t = threadIdx.x;
  float l1 = 0.f, l2 = 0.f, ac = 0.f;
  for (int r = t; r < BATCH; r += 256) {
    float dij = sIJ[r] - sIK[r];
    l1 += softplusf(-dij);
    if (dij >= 0.0f) ac += 1.0f;
    float dst = stIJ[r] - stIK[r];
    l2 += softplusf(-dst);
  }
  double l3 = 0.0;
  for (int p = t; p < NB_M; p += 256) l3 += (double)l3partial[p];
  for (int idx = t; idx < 8192; idx += 256) l3 += (double)HHb[idx] * (double)PPb[idx];
  __shared__ float sh1[4], sh2[4], sh3[4];
  __shared__ double sh4[4];
  for (int off = 32; off > 0; off >>= 1) {
    l1 += __shfl_xor(l1, off);
    l2 += __shfl_xor(l2, off);
    ac += __shfl_xor(ac, off);
    l3 += __shfl_xor(l3, off);
  }
  if ((t & 63) == 0) { sh1[t >> 6] = l1; sh2[t >> 6] = l2; sh3[t >> 6] = ac; sh4[t >> 6] = l3; }
  __syncthreads();
  if (t == 0) {
    double L1 = 0, L2 = 0, AC = 0, L3 = 0;
    for (int i = 0; i < 4; i++) { L1 += sh1[i]; L2 += sh2[i]; AC += sh3[i]; L3 += sh4[i]; }
    L1 /= BATCH; L2 /= BATCH; AC /= BATCH;
    L3 /= ((double)D2 * (double)NOUT);
    out[0] = (float)(L1 + L2 + 0.1 * L3);
    out[1] = (float)L1;
    out[2] = (float)L2;
    out[3] = (float)L3;
    out[4] = (float)AC;
  }
}

extern "C" void kernel_launch(void* const* d_in, const int* in_sizes, int n_in,
                              void* d_out, int out_size, void* d_ws, size_t ws_size,
                              hipStream_t stream) {
  (void)in_sizes; (void)n_in; (void)out_size; (void)ws_size;
  const float* i_f  = (const float*)d_in[0];
  const float* j_f  = (const float*)d_in[1];
  const float* k_f  = (const float*)d_in[2];
  const float* W_t  = (const float*)d_in[3];
  const float* b_t  = (const float*)d_in[4];
  const float* W_b  = (const float*)d_in[5];
  const float* b_b  = (const float*)d_in[6];
  const float* P_n  = (const float*)d_in[7];
  const float* N_n  = (const float*)d_in[8];
  const float* H1   = (const float*)d_in[9];
  const float* H2   = (const float*)d_in[10];
  const float* Mp   = (const float*)d_in[11];
  const float* Mn   = (const float*)d_in[12];
  float* out = (float*)d_out;
  char* ws = (char*)d_ws;

  const size_t OFF_FBF   = 0;
  const size_t OFF_WBFT  = OFF_FBF   + (size_t)3 * BATCH * KP * 2;
  const size_t OFF_PNBFT = OFF_WBFT  + (size_t)2 * HID * KP * 2;
  const size_t OFF_PR    = OFF_PNBFT + (size_t)2 * 64 * D2P * 2;
  const size_t OFF_HROWS = OFF_PR    + (size_t)2 * D2P * 64 * 4;
  const size_t OFF_SIJ   = OFF_HROWS + (size_t)2 * 64 * OUTP * 2;
  const size_t OFF_SIK   = OFF_SIJ   + (size_t)BATCH * 4;
  const size_t OFF_HH    = OFF_SIK   + (size_t)BATCH * 4;
  const size_t OFF_PP    = OFF_HH    + (size_t)2 * 4096 * 4;
  const size_t OFF_STIJ  = OFF_PP    + (size_t)2 * 4096 * 4;
  const size_t OFF_STIK  = OFF_STIJ  + (size_t)BATCH * 4;
  const size_t OFF_SS    = OFF_STIK  + (size_t)BATCH * 4;
  const size_t OFF_CN    = OFF_SS    + 512;
  const size_t OFF_L3P   = OFF_CN    + 512;

  unsigned short* fbf   = (unsigned short*)(ws + OFF_FBF);
  unsigned short* wbfT  = (unsigned short*)(ws + OFF_WBFT);
  unsigned short* pnbfT = (unsigned short*)(ws + OFF_PNBFT);
  float*          Pr    = (float*)(ws + OFF_PR);
  unsigned short* hrows = (unsigned short*)(ws + OFF_HROWS);
  float*  sIJ  = (float*)(ws + OFF_SIJ);
  float*  sIK  = (float*)(ws + OFF_SIK);
  float*  HHb  = (float*)(ws + OFF_HH);
  float*  PPb  = (float*)(ws + OFF_PP);
  float*  stIJ = (float*)(ws + OFF_STIJ);
  float*  stIK = (float*)(ws + OFF_STIK);
  float*  ss   = (float*)(ws + OFF_SS);
  float*  cn   = (float*)(ws + OFF_CN);
  float*  l3p  = (float*)(ws + OFF_L3P);

  // zero: sIJ, sIK, HH, PP (atomic targets) — contiguous
  hipMemsetAsync(ws + OFF_SIJ, 0, (size_t)BATCH * 4 * 2 + (size_t)4 * 4096 * 4, stream);

  k_conv<<<NB_CONV, 256, 0, stream>>>(i_f, j_f, k_f, W_t, W_b, P_n, N_n, H1, H2,
                                      fbf, wbfT, pnbfT, hrows, Pr);
  k_style<<<NB_SS, 256, 0, stream>>>(W_t, b_t, W_b, b_b, P_n, N_n, ss, cn);
  k_m<<<NB_M, 256, 0, stream>>>(hrows, Pr, Mp, Mn, l3p);
  k_emb<<<NB_EMB, 256, 0, stream>>>(fbf, wbfT, b_t, b_b, sIJ, sIK);
  k_sa<<<NB_SA, 256, 0, stream>>>(fbf, pnbfT, cn, ss, stIJ, stIK);
  k_head<<<NB_HEAD, 256, 0, stream>>>(pnbfT, hrows, HHb, PPb);
  k_final<<<1, 256, 0, stream>>>(sIJ, sIK, stIJ, stIK, l3p, HHb, PPb, out);
}